// Round 9
// baseline (111.411 us; speedup 1.0000x reference)
//
#include <hip/hip_runtime.h>
#include <hip/hip_bf16.h>

// CRF NLL via chunk-parallel linear-space scan, register-resident H.
//   q^T_t = q^T_0 (M D_1)...(M D_T);  per chunk: H <- diag(e_t) M^T H.
//
// R8 structural change vs R7 (chunk 44us: LDS round-trip per step -- 6 b128
// reads + 9 b64 writes + waits, 2.9M bank-conflict cycles, occupancy 14.6%):
// use mfma_f32_16x16x16_bf16 (K=16). Its B-layout (n=lane&15, k=quad*4+e)
// EQUALS its C/D-layout (col=lane&15, row=quad*4+reg), so the next step's
// B operand is the current step's C tile packed f32->bf16 IN PLACE.
// H never touches LDS; per step: 27 MFMA + 3 broadcast b128 Etab reads
// (conflict-free) + ~55 VALU scale/pack. 36 states padded to 48 (3 tiles
// of 16 in m, n, k; pad rows/cols provably stay zero).
// Renorm every 4 steps by C(0,0)[1]@lane1 = (M^T H)[1][1] (uniform, >0);
// alpha = logC + log q invariant under any uniform rescale.

namespace {
constexpr int kB = 128;
constexpr int kS = 512;
constexpr int kT = 36;
constexpr int kStart = 34;
constexpr int kEnd = 35;
constexpr int kP = 16;     // chunks per batch
constexpr int kL = 32;     // time-steps per chunk
constexpr int kEStr = 48;  // Etab row stride (floats): rows m 0..47

typedef __bf16 bf16x4 __attribute__((ext_vector_type(4)));
typedef short short4 __attribute__((ext_vector_type(4)));
typedef float f32x4 __attribute__((ext_vector_type(4)));

__device__ __forceinline__ float readlane_f(float v, int lane) {
    return __builtin_bit_cast(float, __builtin_amdgcn_readlane(__builtin_bit_cast(int, v), lane));
}

__device__ __forceinline__ float wave_sum(float v) {
#pragma unroll
    for (int off = 32; off; off >>= 1) v += __shfl_xor(v, off, 64);
    return v;
}

__device__ __forceinline__ int wave_sum_i(int v) {
#pragma unroll
    for (int off = 32; off; off >>= 1) v += __shfl_xor(v, off, 64);
    return v;
}

#define MF16(a, b, c) __builtin_amdgcn_mfma_f32_16x16x16bf16_1k((a), (b), (c), 0, 0, 0)

// ============================ kernel 1: chunks ============================

__global__ __attribute__((amdgpu_flat_work_group_size(64, 64),
                          amdgpu_waves_per_eu(2, 4)))
void crf_chunk_kernel(const float* __restrict__ feats,    // (B,S,T)
                      const float* __restrict__ trans,    // (T,T)
                      const int* __restrict__ mask,       // (B,S)
                      __bf16* __restrict__ Hws,           // (B,P,36,36) bf16
                      float* __restrict__ lscws) {        // (B,P)
    const int b = blockIdx.x;
    const int p = blockIdx.y;
    const int tid = threadIdx.x;
    const int ln = tid & 15;    // n / m-in-tile index
    const int quad = tid >> 4;  // k/row quad index

    __shared__ __align__(16) float Etab[kL * kEStr];  // exp(feats), 1.0 pad

    // ---- sequence length (contiguous-prefix mask) ----
    const int* mb = mask + b * kS;
    int len = 0;
    for (int k = tid; k < kS; k += 64) len += mb[k];
    len = wave_sum_i(len);  // in [256, 512]

    __bf16* Hout = Hws + (size_t)(b * kP + p) * (kT * kT);
    const int cs = (p == 0) ? 1 : p * kL;   // first scan step of chunk
    const int ce = min((p + 1) * kL, len);  // one past last
    const int nsteps = ce - cs;

    if (nsteps <= 0) {  // fully masked chunk -> identity transfer matrix
        for (int idx = tid; idx < kT * kT; idx += 64)
            Hout[idx] = (__bf16)((idx / kT == idx % kT) ? 1.f : 0.f);
        if (tid == 0) lscws[b * kP + p] = 0.f;
        return;
    }

    // ---- stage exp(feats): Etab[tl][m], 1.0 in m-padding (rows 36..47) ----
    const float* fb = feats + ((size_t)b * kS + cs) * kT;  // rows cs..cs+31 all in-bounds
    for (int idx = tid; idx < kL * kEStr; idx += 64) {
        const int tl = idx / kEStr, jj = idx % kEStr;
        Etab[idx] = (jj < kT) ? __expf(fb[tl * kT + jj]) : 1.0f;
    }
    __builtin_amdgcn_s_waitcnt(0);  // LDS writes done (single wave, no barrier needed)

    // ---- A = M^T bf16 frags (fixed): A(rt,kc)[m][k] = exp(trans[k][m]) ----
    // 16x16x16 A-layout: m = lane&15, k = quad*4 + e
    auto afrag = [&](int rt, int kc) {
        bf16x4 r;
        const int m = rt * 16 + ln;
#pragma unroll
        for (int e = 0; e < 4; ++e) {
            const int k = kc * 16 + quad * 4 + e;
            float v = 0.f;
            if (m < kT && k < kT) v = __expf(trans[k * kT + m]);
            r[e] = (__bf16)v;
        }
        return __builtin_bit_cast(short4, r);
    };
    const short4 a00 = afrag(0, 0), a01 = afrag(0, 1), a02 = afrag(0, 2);
    const short4 a10 = afrag(1, 0), a11 = afrag(1, 1), a12 = afrag(1, 2);
    const short4 a20 = afrag(2, 0), a21 = afrag(2, 1), a22 = afrag(2, 2);

    // ---- B = H, register-resident; init H = I ----
    // B-layout(kc,ct): k = kc*16 + quad*4 + e, n = ct*16 + ln
    auto binit = [&](int kc, int ct) {
        bf16x4 r;
        const int n = ct * 16 + ln;
#pragma unroll
        for (int e = 0; e < 4; ++e) {
            const int k = kc * 16 + quad * 4 + e;
            r[e] = (__bf16)((k == n && k < kT) ? 1.f : 0.f);
        }
        return __builtin_bit_cast(short4, r);
    };
    short4 b00 = binit(0, 0), b01 = binit(0, 1), b02 = binit(0, 2);
    short4 b10 = binit(1, 0), b11 = binit(1, 1), b12 = binit(1, 2);
    short4 b20 = binit(2, 0), b21 = binit(2, 1), b22 = binit(2, 2);

    // ---- main chunk loop: H in registers, no LDS round-trip ----
    float logC = 0.f;
    const f32x4 z = {0.f, 0.f, 0.f, 0.f};
    for (int tl = 0; tl < nsteps; ++tl) {
        // row scales e[m], m = rt*16 + quad*4 + reg (broadcast reads, 0 conflicts)
        const f32x4 e0 = *(const f32x4*)&Etab[tl * kEStr + 0 + quad * 4];
        const f32x4 e1 = *(const f32x4*)&Etab[tl * kEStr + 16 + quad * 4];
        const f32x4 e2 = *(const f32x4*)&Etab[tl * kEStr + 32 + quad * 4];

        f32x4 c00 = MF16(a00, b00, z); f32x4 c01 = MF16(a00, b01, z); f32x4 c02 = MF16(a00, b02, z);
        c00 = MF16(a01, b10, c00);     c01 = MF16(a01, b11, c01);     c02 = MF16(a01, b12, c02);
        c00 = MF16(a02, b20, c00);     c01 = MF16(a02, b21, c01);     c02 = MF16(a02, b22, c02);
        f32x4 c10 = MF16(a10, b00, z); f32x4 c11 = MF16(a10, b01, z); f32x4 c12 = MF16(a10, b02, z);
        c10 = MF16(a11, b10, c10);     c11 = MF16(a11, b11, c11);     c12 = MF16(a11, b12, c12);
        c10 = MF16(a12, b20, c10);     c11 = MF16(a12, b21, c11);     c12 = MF16(a12, b22, c12);
        f32x4 c20 = MF16(a20, b00, z); f32x4 c21 = MF16(a20, b01, z); f32x4 c22 = MF16(a20, b02, z);
        c20 = MF16(a21, b10, c20);     c21 = MF16(a21, b11, c21);     c22 = MF16(a21, b12, c22);
        c20 = MF16(a22, b20, c20);     c21 = MF16(a22, b21, c21);     c22 = MF16(a22, b22, c22);

        // renorm every 4 steps by (M^T H)[1][1] (uniform, positive)
        float rs = 1.f;
        if ((tl & 3) == 3) {
            const float s = readlane_f(c00[1], 1);
            rs = __builtin_amdgcn_rcpf(s);
            logC += __logf(s);
        }
        const f32x4 s0 = e0 * rs, s1 = e1 * rs, s2 = e2 * rs;

        // scale rows + pack in place: B(kc=rt, ct) = bf16(C(rt,ct) * s_rt)
#define PK(cv, sv) ({ const f32x4 t_ = (cv) * (sv); bf16x4 h_;                  \
        h_[0] = (__bf16)t_[0]; h_[1] = (__bf16)t_[1];                           \
        h_[2] = (__bf16)t_[2]; h_[3] = (__bf16)t_[3];                           \
        __builtin_bit_cast(short4, h_); })
        b00 = PK(c00, s0); b01 = PK(c01, s0); b02 = PK(c02, s0);
        b10 = PK(c10, s1); b11 = PK(c11, s1); b12 = PK(c12, s1);
        b20 = PK(c20, s2); b21 = PK(c21, s2); b22 = PK(c22, s2);
#undef PK
    }

    // ---- store H (bf16): B(kc,ct) holds H[k = kc*16+quad*4+e][n = ct*16+ln] ----
#define STOREB(Bv, kc, ct) {                                                    \
    const bf16x4 h_ = __builtin_bit_cast(bf16x4, Bv);                           \
    const int n_ = (ct)*16 + ln;                                                \
    _Pragma("unroll") for (int e = 0; e < 4; ++e) {                             \
        const int m_ = (kc)*16 + quad * 4 + e;                                  \
        if (m_ < kT && n_ < kT) Hout[m_ * kT + n_] = h_[e]; } }
    STOREB(b00, 0, 0) STOREB(b01, 0, 1) STOREB(b02, 0, 2)
    STOREB(b10, 1, 0) STOREB(b11, 1, 1) STOREB(b12, 1, 2)
    STOREB(b20, 2, 0) STOREB(b21, 2, 1) STOREB(b22, 2, 2)
#undef STOREB
    if (tid == 0) lscws[b * kP + p] = logC;
}

// ============================ kernel 2: combine ============================

// term n of the 36-dot: accumulator a (0..3), h-vector g (= n/4), component c (= n%4)
#define FORK36(X) \
    X(0,0,0,0) X(1,1,0,1) X(2,2,0,2) X(3,3,0,3) \
    X(4,0,1,0) X(5,1,1,1) X(6,2,1,2) X(7,3,1,3) \
    X(8,0,2,0) X(9,1,2,1) X(10,2,2,2) X(11,3,2,3) \
    X(12,0,3,0) X(13,1,3,1) X(14,2,3,2) X(15,3,3,3) \
    X(16,0,4,0) X(17,1,4,1) X(18,2,4,2) X(19,3,4,3) \
    X(20,0,5,0) X(21,1,5,1) X(22,2,5,2) X(23,3,5,3) \
    X(24,0,6,0) X(25,1,6,1) X(26,2,6,2) X(27,3,6,3) \
    X(28,0,7,0) X(29,1,7,1) X(30,2,7,2) X(31,3,7,3) \
    X(32,0,8,0) X(33,1,8,1) X(34,2,8,2) X(35,3,8,3)

__global__ __attribute__((amdgpu_flat_work_group_size(64, 64),
                          amdgpu_waves_per_eu(1, 1)))
void crf_combine_kernel(const float* __restrict__ feats,
                        const float* __restrict__ trans,
                        const int* __restrict__ mask,
                        const int* __restrict__ tags,
                        const __bf16* __restrict__ Hws,
                        const float* __restrict__ lscws,
                        float* __restrict__ out) {
    const int b = blockIdx.x;
    const int j = threadIdx.x;
    const float* fbase = feats + (size_t)b * kS * kT;
    const int* mb = mask + b * kS;
    const int* tb = tags + b * kS;

    int len = 0;
    for (int k = j; k < kS; k += 64) len += mb[k];
    len = wave_sum_i(len);

    const float ME = (j < kT) ? __expf(trans[j * kT + kEnd]) : 0.f;

    // init: alpha0 = feats[b,0,:] + trans[START,:]
    float a0 = -1e30f;
    if (j < kT) a0 = fbase[j] + trans[kStart * kT + j];
    float C = readlane_f(a0, 0);
    float q = __expf(a0 - C);  // lanes >= 36 -> 0

    const int jr = (j < kT) ? j : 0;  // clamped row for loads
#pragma unroll
    for (int p = 0; p < kP; ++p) {
        const __bf16* rp = Hws + ((size_t)(b * kP + p) * kT + jr) * kT;  // 8B-aligned row
        const bf16x4 h0 = *(const bf16x4*)(rp + 0);
        const bf16x4 h1 = *(const bf16x4*)(rp + 4);
        const bf16x4 h2 = *(const bf16x4*)(rp + 8);
        const bf16x4 h3 = *(const bf16x4*)(rp + 12);
        const bf16x4 h4 = *(const bf16x4*)(rp + 16);
        const bf16x4 h5 = *(const bf16x4*)(rp + 20);
        const bf16x4 h6 = *(const bf16x4*)(rp + 24);
        const bf16x4 h7 = *(const bf16x4*)(rp + 28);
        const bf16x4 h8 = *(const bf16x4*)(rp + 32);
#define BRD2(n, a, g, c) const float bb##n = readlane_f(q, n);
        FORK36(BRD2)
#undef BRD2
        float v0 = 0.f, v1 = 0.f, v2 = 0.f, v3 = 0.f;
#define FMA2(n, a, g, c) v##a = fmaf(bb##n, (float)h##g[c], v##a);
        FORK36(FMA2)
#undef FMA2
        const float qn = (v0 + v1) + (v2 + v3);
        q = (j < kT) ? qn : 0.f;
        C += lscws[b * kP + p];
        const float s = readlane_f(q, 0);  // positive (state-0 alpha)
        q *= __builtin_amdgcn_rcpf(s);
        C += __logf(s);
    }

    // forward score
    const float ssum = wave_sum(q * ME);
    const float forward_b = C + __logf(ssum);

    // gold score
    float g = 0.f;
    for (int k = j; k < kS; k += 64) {
        if (k < len) {
            const int tg = tb[k];
            const int pv = (k == 0) ? kStart : tb[k - 1];
            g += fbase[(size_t)k * kT + tg] + trans[pv * kT + tg];
        }
    }
    g = wave_sum(g);

    if (j == 0) {
        g += trans[tb[len - 1] * kT + kEnd];
        atomicAdd(out, (forward_b - g) * (1.0f / kB));
    }
}

}  // namespace

extern "C" void kernel_launch(void* const* d_in, const int* in_sizes, int n_in,
                              void* d_out, int out_size, void* d_ws, size_t ws_size,
                              hipStream_t stream) {
    const float* feats = (const float*)d_in[0];
    const float* trans = (const float*)d_in[1];
    const int* mask = (const int*)d_in[2];
    const int* tags = (const int*)d_in[3];
    float* out = (float*)d_out;

    __bf16* Hws = (__bf16*)d_ws;                               // B*P*36*36 bf16
    float* lscws = (float*)(Hws + (size_t)kB * kP * kT * kT);  // B*P fp32

    (void)hipMemsetAsync(out, 0, sizeof(float), stream);
    crf_chunk_kernel<<<dim3(kB, kP), dim3(64), 0, stream>>>(feats, trans, mask, Hws, lscws);
    crf_combine_kernel<<<dim3(kB), dim3(64), 0, stream>>>(feats, trans, mask, tags,
                                                          Hws, lscws, out);
}

// Round 10
// 109.551 us; speedup vs baseline: 1.0170x; 1.0170x over previous
//
#include <hip/hip_runtime.h>
#include <hip/hip_bf16.h>

// CRF NLL via chunk-parallel linear-space scan, register-resident H.
//   q^T_t = q^T_0 (M D_1)...(M D_T);  per chunk: H <- diag(e_t) M^T H.
// mfma_f32_16x16x16_bf16: B-layout == C/D-layout, so next step's B operand is
// current step's C tile packed f32->bf16 in place (no LDS for H, 0 conflicts
// -- verified R8).
//
// R9 vs R8 (R8: chunk 42us, MfmaUtil 17%, VALUBusy 17%, occupancy 1.1
// wave/SIMD -> ~70% of wave cycles are exposed latency; prologue staging loop
// serialized on HBM latency via div-indexed non-unrolled loop):
//  - kP 16->32 (kL=16): 4096 waves = 16 blocks/CU = 4/SIMD target; halves
//    per-wave serial depth. Stalls filled by co-resident waves.
//  - staging: kEStr=64 shift indexing, constant-trip #pragma unroll -> all 16
//    feats loads issued as one vmcnt batch instead of 24 serial round-trips.
//  - renorm reads stale H[1,1] from the PREVIOUS pack's b00 register (VALU
//    value, readlane at loop top) -> no MFMA-dest->VALU hazard on the chain.
//    Any uniform positive rescale is exact (its log is re-added to logC).

namespace {
constexpr int kB = 128;
constexpr int kS = 512;
constexpr int kT = 36;
constexpr int kStart = 34;
constexpr int kEnd = 35;
constexpr int kP = 32;     // chunks per batch
constexpr int kL = 16;     // time-steps per chunk
constexpr int kEStr = 64;  // Etab row stride (floats), shift-indexed

typedef __bf16 bf16x4 __attribute__((ext_vector_type(4)));
typedef short short4v __attribute__((ext_vector_type(4)));
typedef float f32x4 __attribute__((ext_vector_type(4)));
typedef int int2v __attribute__((ext_vector_type(2)));

__device__ __forceinline__ float readlane_f(float v, int lane) {
    return __builtin_bit_cast(float, __builtin_amdgcn_readlane(__builtin_bit_cast(int, v), lane));
}

__device__ __forceinline__ float wave_sum(float v) {
#pragma unroll
    for (int off = 32; off; off >>= 1) v += __shfl_xor(v, off, 64);
    return v;
}

__device__ __forceinline__ int wave_sum_i(int v) {
#pragma unroll
    for (int off = 32; off; off >>= 1) v += __shfl_xor(v, off, 64);
    return v;
}

#define MF16(a, b, c) __builtin_amdgcn_mfma_f32_16x16x16bf16_1k((a), (b), (c), 0, 0, 0)

// ============================ kernel 1: chunks ============================

__global__ __attribute__((amdgpu_flat_work_group_size(64, 64),
                          amdgpu_waves_per_eu(2, 4)))
void crf_chunk_kernel(const float* __restrict__ feats,    // (B,S,T)
                      const float* __restrict__ trans,    // (T,T)
                      const int* __restrict__ mask,       // (B,S)
                      __bf16* __restrict__ Hws,           // (B,P,36,36) bf16
                      float* __restrict__ lscws) {        // (B,P)
    const int b = blockIdx.x;
    const int p = blockIdx.y;
    const int tid = threadIdx.x;
    const int ln = tid & 15;    // n / m-in-tile index
    const int quad = tid >> 4;  // k/row quad index

    __shared__ __align__(16) float Etab[kL * kEStr];  // exp(feats), 1.0 pad

    // ---- sequence length (contiguous-prefix mask) ----
    const int* mb = mask + b * kS;
    int len = 0;
#pragma unroll
    for (int k = 0; k < kS / 64; ++k) len += mb[k * 64 + tid];
    len = wave_sum_i(len);  // in [256, 512]

    __bf16* Hout = Hws + (size_t)(b * kP + p) * (kT * kT);
    const int cs = (p == 0) ? 1 : p * kL;   // first scan step of chunk
    const int ce = min((p + 1) * kL, len);  // one past last
    const int nsteps = ce - cs;

    if (nsteps <= 0) {  // fully masked chunk -> identity transfer matrix
        for (int idx = tid; idx < kT * kT; idx += 64)
            Hout[idx] = (__bf16)((idx / kT == idx % kT) ? 1.f : 0.f);
        if (tid == 0) lscws[b * kP + p] = 0.f;
        return;
    }

    // ---- stage exp(feats): Etab[tl][m], 1.0 in m-padding; batched loads ----
    const float* fb = feats + ((size_t)b * kS + cs) * kT;  // rows cs..cs+kL-1 in-bounds
    {
        float stage[kL];
#pragma unroll
        for (int it = 0; it < kL; ++it)  // all loads issue before first use
            stage[it] = (tid < kT) ? fb[it * kT + tid] : 0.f;
#pragma unroll
        for (int it = 0; it < kL; ++it)
            Etab[it * kEStr + tid] = (tid < kT) ? __expf(stage[it]) : 1.0f;
    }
    __builtin_amdgcn_s_waitcnt(0);  // single wave: LDS writes visible to self

    // ---- A = M^T bf16 frags (fixed): A(rt,kc)[m][k] = exp(trans[k][m]) ----
    // 16x16x16 A-layout: m = lane&15, k = quad*4 + e
    auto afrag = [&](int rt, int kc) {
        bf16x4 r;
        const int m = rt * 16 + ln;
#pragma unroll
        for (int e = 0; e < 4; ++e) {
            const int k = kc * 16 + quad * 4 + e;
            float v = 0.f;
            if (m < kT && k < kT) v = __expf(trans[k * kT + m]);
            r[e] = (__bf16)v;
        }
        return __builtin_bit_cast(short4v, r);
    };
    const short4v a00 = afrag(0, 0), a01 = afrag(0, 1), a02 = afrag(0, 2);
    const short4v a10 = afrag(1, 0), a11 = afrag(1, 1), a12 = afrag(1, 2);
    const short4v a20 = afrag(2, 0), a21 = afrag(2, 1), a22 = afrag(2, 2);

    // ---- B = H, register-resident; init H = I ----
    // B-layout(kc,ct): k = kc*16 + quad*4 + e, n = ct*16 + ln
    auto binit = [&](int kc, int ct) {
        bf16x4 r;
        const int n = ct * 16 + ln;
#pragma unroll
        for (int e = 0; e < 4; ++e) {
            const int k = kc * 16 + quad * 4 + e;
            r[e] = (__bf16)((k == n && k < kT) ? 1.f : 0.f);
        }
        return __builtin_bit_cast(short4v, r);
    };
    short4v b00 = binit(0, 0), b01 = binit(0, 1), b02 = binit(0, 2);
    short4v b10 = binit(1, 0), b11 = binit(1, 1), b12 = binit(1, 2);
    short4v b20 = binit(2, 0), b21 = binit(2, 1), b22 = binit(2, 2);

    // ---- main chunk loop: H in registers, no LDS round-trip ----
    float logC = 0.f;
    const f32x4 z = {0.f, 0.f, 0.f, 0.f};
    for (int tl = 0; tl < nsteps; ++tl) {
        // stale renorm source: H[1,1] = b00 elem1 @ lane1 (VALU value, no
        // MFMA hazard). bf16 bits in high half of int2.x.
        const int w11 = __builtin_amdgcn_readlane(__builtin_bit_cast(int2v, b00).x, 1);
        // row scales e[m], m = rt*16 + quad*4 + reg (broadcast, conflict-free)
        const float* et = &Etab[tl * kEStr + quad * 4];
        const f32x4 e0 = *(const f32x4*)(et + 0);
        const f32x4 e1 = *(const f32x4*)(et + 16);
        const f32x4 e2 = *(const f32x4*)(et + 32);

        f32x4 c00 = MF16(a00, b00, z); f32x4 c01 = MF16(a00, b01, z); f32x4 c02 = MF16(a00, b02, z);
        c00 = MF16(a01, b10, c00);     c01 = MF16(a01, b11, c01);     c02 = MF16(a01, b12, c02);
        c00 = MF16(a02, b20, c00);     c01 = MF16(a02, b21, c01);     c02 = MF16(a02, b22, c02);
        f32x4 c10 = MF16(a10, b00, z); f32x4 c11 = MF16(a10, b01, z); f32x4 c12 = MF16(a10, b02, z);
        c10 = MF16(a11, b10, c10);     c11 = MF16(a11, b11, c11);     c12 = MF16(a11, b12, c12);
        c10 = MF16(a12, b20, c10);     c11 = MF16(a12, b21, c11);     c12 = MF16(a12, b22, c12);
        f32x4 c20 = MF16(a20, b00, z); f32x4 c21 = MF16(a20, b01, z); f32x4 c22 = MF16(a20, b02, z);
        c20 = MF16(a21, b10, c20);     c21 = MF16(a21, b11, c21);     c22 = MF16(a21, b12, c22);
        c20 = MF16(a22, b20, c20);     c21 = MF16(a22, b21, c21);     c22 = MF16(a22, b22, c22);

        // renorm every 4 steps by stale H[1,1] (uniform, positive)
        float rs = 1.f;
        if ((tl & 3) == 3) {
            const float s = __builtin_bit_cast(float, (unsigned)w11 & 0xFFFF0000u);
            rs = __builtin_amdgcn_rcpf(s);
            logC += __logf(s);
        }
        const f32x4 s0 = e0 * rs, s1 = e1 * rs, s2 = e2 * rs;

        // scale rows + pack in place: B(kc=rt, ct) = bf16(C(rt,ct) * s_rt)
#define PK(cv, sv) ({ const f32x4 t_ = (cv) * (sv); bf16x4 h_;                  \
        h_[0] = (__bf16)t_[0]; h_[1] = (__bf16)t_[1];                           \
        h_[2] = (__bf16)t_[2]; h_[3] = (__bf16)t_[3];                           \
        __builtin_bit_cast(short4v, h_); })
        b00 = PK(c00, s0); b01 = PK(c01, s0); b02 = PK(c02, s0);
        b10 = PK(c10, s1); b11 = PK(c11, s1); b12 = PK(c12, s1);
        b20 = PK(c20, s2); b21 = PK(c21, s2); b22 = PK(c22, s2);
#undef PK
    }

    // ---- store H (bf16): B(kc,ct) holds H[k = kc*16+quad*4+e][n = ct*16+ln] ----
#define STOREB(Bv, kc, ct) {                                                    \
    const bf16x4 h_ = __builtin_bit_cast(bf16x4, Bv);                           \
    const int n_ = (ct)*16 + ln;                                                \
    _Pragma("unroll") for (int e = 0; e < 4; ++e) {                             \
        const int m_ = (kc)*16 + quad * 4 + e;                                  \
        if (m_ < kT && n_ < kT) Hout[m_ * kT + n_] = h_[e]; } }
    STOREB(b00, 0, 0) STOREB(b01, 0, 1) STOREB(b02, 0, 2)
    STOREB(b10, 1, 0) STOREB(b11, 1, 1) STOREB(b12, 1, 2)
    STOREB(b20, 2, 0) STOREB(b21, 2, 1) STOREB(b22, 2, 2)
#undef STOREB
    if (tid == 0) lscws[b * kP + p] = logC;
}

// ============================ kernel 2: combine ============================

// term n of the 36-dot: accumulator a (0..3), h-vector g (= n/4), component c (= n%4)
#define FORK36(X) \
    X(0,0,0,0) X(1,1,0,1) X(2,2,0,2) X(3,3,0,3) \
    X(4,0,1,0) X(5,1,1,1) X(6,2,1,2) X(7,3,1,3) \
    X(8,0,2,0) X(9,1,2,1) X(10,2,2,2) X(11,3,2,3) \
    X(12,0,3,0) X(13,1,3,1) X(14,2,3,2) X(15,3,3,3) \
    X(16,0,4,0) X(17,1,4,1) X(18,2,4,2) X(19,3,4,3) \
    X(20,0,5,0) X(21,1,5,1) X(22,2,5,2) X(23,3,5,3) \
    X(24,0,6,0) X(25,1,6,1) X(26,2,6,2) X(27,3,6,3) \
    X(28,0,7,0) X(29,1,7,1) X(30,2,7,2) X(31,3,7,3) \
    X(32,0,8,0) X(33,1,8,1) X(34,2,8,2) X(35,3,8,3)

__global__ __attribute__((amdgpu_flat_work_group_size(64, 64),
                          amdgpu_waves_per_eu(1, 1)))
void crf_combine_kernel(const float* __restrict__ feats,
                        const float* __restrict__ trans,
                        const int* __restrict__ mask,
                        const int* __restrict__ tags,
                        const __bf16* __restrict__ Hws,
                        const float* __restrict__ lscws,
                        float* __restrict__ out) {
    const int b = blockIdx.x;
    const int j = threadIdx.x;
    const float* fbase = feats + (size_t)b * kS * kT;
    const int* mb = mask + b * kS;
    const int* tb = tags + b * kS;

    int len = 0;
#pragma unroll
    for (int k = 0; k < kS / 64; ++k) len += mb[k * 64 + j];
    len = wave_sum_i(len);

    const float ME = (j < kT) ? __expf(trans[j * kT + kEnd]) : 0.f;

    // init: alpha0 = feats[b,0,:] + trans[START,:]
    float a0 = -1e30f;
    if (j < kT) a0 = fbase[j] + trans[kStart * kT + j];
    float C = readlane_f(a0, 0);
    float q = __expf(a0 - C);  // lanes >= 36 -> 0

    const int jr = (j < kT) ? j : 0;  // clamped row for loads
#pragma unroll 4
    for (int p = 0; p < kP; ++p) {
        const __bf16* rp = Hws + ((size_t)(b * kP + p) * kT + jr) * kT;  // 8B-aligned row
        const bf16x4 h0 = *(const bf16x4*)(rp + 0);
        const bf16x4 h1 = *(const bf16x4*)(rp + 4);
        const bf16x4 h2 = *(const bf16x4*)(rp + 8);
        const bf16x4 h3 = *(const bf16x4*)(rp + 12);
        const bf16x4 h4 = *(const bf16x4*)(rp + 16);
        const bf16x4 h5 = *(const bf16x4*)(rp + 20);
        const bf16x4 h6 = *(const bf16x4*)(rp + 24);
        const bf16x4 h7 = *(const bf16x4*)(rp + 28);
        const bf16x4 h8 = *(const bf16x4*)(rp + 32);
#define BRD2(n, a, g, c) const float bb##n = readlane_f(q, n);
        FORK36(BRD2)
#undef BRD2
        float v0 = 0.f, v1 = 0.f, v2 = 0.f, v3 = 0.f;
#define FMA2(n, a, g, c) v##a = fmaf(bb##n, (float)h##g[c], v##a);
        FORK36(FMA2)
#undef FMA2
        const float qn = (v0 + v1) + (v2 + v3);
        q = (j < kT) ? qn : 0.f;
        C += lscws[b * kP + p];
        const float s = readlane_f(q, 0);  // positive (state-0 alpha)
        q *= __builtin_amdgcn_rcpf(s);
        C += __logf(s);
    }

    // forward score
    const float ssum = wave_sum(q * ME);
    const float forward_b = C + __logf(ssum);

    // gold score
    float g = 0.f;
    for (int k = j; k < kS; k += 64) {
        if (k < len) {
            const int tg = tb[k];
            const int pv = (k == 0) ? kStart : tb[k - 1];
            g += fbase[(size_t)k * kT + tg] + trans[pv * kT + tg];
        }
    }
    g = wave_sum(g);

    if (j == 0) {
        g += trans[tb[len - 1] * kT + kEnd];
        atomicAdd(out, (forward_b - g) * (1.0f / kB));
    }
}

}  // namespace

extern "C" void kernel_launch(void* const* d_in, const int* in_sizes, int n_in,
                              void* d_out, int out_size, void* d_ws, size_t ws_size,
                              hipStream_t stream) {
    const float* feats = (const float*)d_in[0];
    const float* trans = (const float*)d_in[1];
    const int* mask = (const int*)d_in[2];
    const int* tags = (const int*)d_in[3];
    float* out = (float*)d_out;

    __bf16* Hws = (__bf16*)d_ws;                               // B*P*36*36 bf16 = 10.6 MB
    float* lscws = (float*)(Hws + (size_t)kB * kP * kT * kT);  // B*P fp32

    (void)hipMemsetAsync(out, 0, sizeof(float), stream);
    crf_chunk_kernel<<<dim3(kB, kP), dim3(64), 0, stream>>>(feats, trans, mask, Hws, lscws);
    crf_combine_kernel<<<dim3(kB), dim3(64), 0, stream>>>(feats, trans, mask, tags,
                                                          Hws, lscws, out);
}